// Round 1
// baseline (204.290 us; speedup 1.0000x reference)
//
#include <hip/hip_runtime.h>

// YOLOv1 loss: pred/label (16384, 30, 7, 7) fp32 -> scalar.
// R7: FUSE class+box+weights into ONE wave-per-record kernel.
//   Evidence: harness fills sustain 6.6 TB/s writes; our kernels pin at
//   ~2.4 TB/s with all pipes idle => latency/issue-structure bound, not BW.
//   Fix: each wave owns exactly ONE record and issues ALL ~25 independent
//   float2 loads up front (box stage 8 + class 16 + w49 1) -> max MLP,
//   pred read as one contiguous 5.9 KB stream per wave. Dropped
//   __builtin_nontemporal_load (the 6.3 TB/s ubench ceiling used regular
//   loads; nt was common to all six pinned structures). Box gather stays
//   wave-private LDS (no __syncthreads), class keeps mod-49 shfl weights.

typedef float v2f __attribute__((ext_vector_type(2)));

#define NBATCH 16384
#define RECF 1470          // floats per record
#define BLOCK 256
#define GRID (NBATCH / 4)  // 4096 blocks: 4 waves/block, 1 record per wave

__device__ __forceinline__ float sq(float x) { return x * x; }

__device__ __forceinline__ float block_reduce(float v, float* smem, int tid) {
#pragma unroll
    for (int off = 32; off > 0; off >>= 1) v += __shfl_down(v, off, 64);
    const int lane = tid & 63, wave = tid >> 6;
    if (lane == 0) smem[wave] = v;
    __syncthreads();
    return smem[0] + smem[1] + smem[2] + smem[3];
}

// ---------------- fused: class + box, one record per wave ----------------
__global__ __launch_bounds__(BLOCK) void k_fused(const float* __restrict__ pred,
                                                 const float* __restrict__ label,
                                                 float* __restrict__ partials) {
    __shared__ float lds[4][960];   // per wave: [0,490) pred ch0-9, [496,938) label ch0-8
    __shared__ float smem[4];
    const int tid = threadIdx.x, lane = tid & 63, wv = tid >> 6;
    const int rec = blockIdx.x * 4 + wv;          // one record per wave, exact cover
    float* ldsw = &lds[wv][0];
    v2f* wp2 = (v2f*)ldsw;          // 245 pairs: pred ch0-9
    v2f* wl2 = (v2f*)(ldsw + 496);  // 221 pairs: label ch0-8

    const v2f* gp = (const v2f*)(pred + (size_t)rec * RECF);
    const v2f* gl = (const v2f*)(label + (size_t)rec * RECF);

    // ---- issue ALL loads up front (independent; ~25 outstanding per wave) ----
    v2f sp[4], sl[4];               // box-region stage (pairs [0,245) / [0,221))
#pragma unroll
    for (int i = 0; i < 4; ++i) {
        int idx = i * 64 + lane;
        sp[i] = (idx < 245) ? gp[idx] : (v2f){0.0f, 0.0f};
        sl[i] = (idx < 221) ? gl[idx] : (v2f){0.0f, 0.0f};
    }
    v2f cpv[8], clv[8];             // class region: pairs [245,735) = floats [490,1470)
#pragma unroll
    for (int i = 0; i < 8; ++i) {
        int k = i * 64 + lane;
        if (k < 490) {
            cpv[i] = gp[245 + k];
            clv[i] = gl[245 + k];
        } else {
            cpv[i] = (v2f){0.0f, 0.0f};
            clv[i] = (v2f){0.0f, 0.0f};
        }
    }
    // 49 objectness weights (exactly 0.0/1.0); same cachelines as the label stage.
    float w49 = (lane < 49) ? ((const float*)gl)[196 + lane] : 0.0f;

    // ---- stage box region to wave-private LDS (frees sp/sl early) ----
#pragma unroll
    for (int i = 0; i < 4; ++i) {
        int idx = i * 64 + lane;
        if (idx < 245) wp2[idx] = sp[i];
        if (idx < 221) wl2[idx] = sl[i];
    }

    // ---- class term (register stream + shfl weights, no LDS) ----
    float acc = 0.0f;
    int c = (2 * lane) % 49;        // cell of class element m = 2*(i*64+lane)
#pragma unroll
    for (int i = 0; i < 8; ++i) {
        float w0 = __shfl(w49, c, 64);             // bpermute
        int cn = (c == 48) ? 0 : c + 1;
        float w1 = __shfl(w49, cn, 64);
        float d0 = cpv[i].x - clv[i].x, d1 = cpv[i].y - clv[i].y;
        acc += w0 * d0 * d0 + w1 * d1 * d1;
        c += 30; if (c >= 49) c -= 49;             // m += 128; 128 mod 49 = 30
    }

    // ---- box term (wave-private LDS gather; no __syncthreads) ----
    asm volatile("s_waitcnt lgkmcnt(0)" ::: "memory");
    if (lane < 49) {
        const int rr = lane / 7, cc = lane - rr * 7;
        const float fr = (float)rr, fcl = (float)cc;
        const float inv7 = 1.0f / 7.0f;

        float p[10], l[9];
#pragma unroll
        for (int ch = 0; ch < 10; ++ch) p[ch] = ldsw[ch * 49 + lane];
#pragma unroll
        for (int ch = 0; ch < 9; ++ch) l[ch] = ldsw[496 + ch * 49 + lane];

        float lcx = (l[0] + fcl) * inv7;
        float lcy = (l[1] + fr) * inv7;
        float lhw = l[2] * 0.5f, lhh = l[3] * 0.5f;
        float lx1 = lcx - lhw, ly1 = lcy - lhh;
        float lx2 = lcx + lhw, ly2 = lcy + lhh;
        float larea = (lx2 - lx1) * (ly2 - ly1);

        float cx1 = (p[0] + fcl) * inv7, cy1 = (p[1] + fr) * inv7;
        float x11 = cx1 - p[2] * 0.5f, y11 = cy1 - p[3] * 0.5f;
        float x12 = cx1 + p[2] * 0.5f, y12 = cy1 + p[3] * 0.5f;
        float iw1 = fmaxf(fminf(x12, lx2) - fmaxf(x11, lx1), 0.0f);
        float ih1 = fmaxf(fminf(y12, ly2) - fmaxf(y11, ly1), 0.0f);
        float int1 = iw1 * ih1;
        float a1 = (x12 - x11) * (y12 - y11);
        float iou1 = int1 / (a1 + larea - int1 + 1e-10f);

        float cx2 = (p[5] + fcl) * inv7, cy2 = (p[6] + fr) * inv7;
        float x21 = cx2 - p[7] * 0.5f, y21 = cy2 - p[8] * 0.5f;
        float x22 = cx2 + p[7] * 0.5f, y22 = cy2 + p[8] * 0.5f;
        float iw2 = fmaxf(fminf(x22, lx2) - fmaxf(x21, lx1), 0.0f);
        float ih2 = fmaxf(fminf(y22, ly2) - fmaxf(y21, ly1), 0.0f);
        float int2 = iw2 * ih2;
        float a2 = (x22 - x21) * (y22 - y21);
        float iou2 = int2 / (a2 + larea - int2 + 1e-10f);

        bool ch1 = iou1 >= iou2;

        float coord1 = 5.0f * (sq(p[0] - l[0]) + sq(p[1] - l[1]))
                     + sq(sqrtf(p[2]) - sqrtf(l[2])) + sq(sqrtf(p[3]) - sqrtf(l[3]));
        float coord2 = 5.0f * (sq(p[5] - l[5]) + sq(p[6] - l[6]))
                     + sq(sqrtf(p[7]) - sqrtf(l[7])) + sq(sqrtf(p[8]) - sqrtf(l[8]));
        float obj1 = sq(p[4] - iou1);
        float obj2 = sq(p[9] - iou2);

        float obj_cell = (ch1 ? coord1 : coord2)
                       + (ch1 ? obj1 : obj2)
                       + 0.5f * (ch1 ? obj2 : obj1);   // class term added above
        float noobj_cell = 0.5f * sq(p[4] + p[9]);

        acc += (l[4] == 1.0f) ? obj_cell : noobj_cell;
    }

    float s = block_reduce(acc, smem, tid);
    if (tid == 0) partials[blockIdx.x] = s;
}

// ---------------- final reduce: 4096 partials ----------------
__global__ __launch_bounds__(BLOCK) void k_reduce(const float* __restrict__ partials,
                                                  float* __restrict__ out) {
    __shared__ float smem[4];
    float s = 0.0f;
#pragma unroll
    for (int it = 0; it < GRID / BLOCK; ++it)   // 16 independent loads
        s += partials[it * BLOCK + threadIdx.x];
    float t = block_reduce(s, smem, threadIdx.x);
    if (threadIdx.x == 0) out[0] = t * (1.0f / (float)NBATCH);
}

extern "C" void kernel_launch(void* const* d_in, const int* in_sizes, int n_in,
                              void* d_out, int out_size, void* d_ws, size_t ws_size,
                              hipStream_t stream) {
    const float* pred  = (const float*)d_in[0];
    const float* label = (const float*)d_in[1];
    float* out = (float*)d_out;
    float* part = (float*)d_ws;          // 4096 floats

    k_fused<<<GRID, BLOCK, 0, stream>>>(pred, label, part);
    k_reduce<<<1, BLOCK, 0, stream>>>(part, out);
}